// Round 1
// baseline (3541.699 us; speedup 1.0000x reference)
//
#include <hip/hip_runtime.h>
#include <cmath>

// Problem constants (from reference): B=32, C=64, T=8192, H=256
#define B_  32
#define C_  64
#define T_  8192
#define H_  256
#define TT  64        // time-tile per block
#define XSW 76        // xs row width (floats): t0-7 .. t0+68
#define R1W 72        // rs1 row width: j=0..71 <-> t = t0-4+j
#define R2W 68        // rs2 row width: j=0..67 <-> t = t0-2+j  (66 valid)

// LDS layout (floats): xs[64][76] | r1[256][72] | r2[256][68] | pad
// total = 4864 + 18432 + 17408 + 16 = 40720 floats = 162,880 B (<= 160 KiB)
#define SMEM_F (C_*XSW + H_*R1W + H_*R2W + 16)

__global__ __launch_bounds__(512, 2)
void arflow_fused(const float* __restrict__ x,
                  const float* __restrict__ w_in,  const float* __restrict__ b_in,
                  const float* __restrict__ w_mid, const float* __restrict__ b_mid,
                  const float* __restrict__ w_out, const float* __restrict__ b_out,
                  const float* __restrict__ alpha, const float* __restrict__ beta,
                  float* __restrict__ out)
{
    __shared__ __align__(16) float smem[SMEM_F];
    float* xs = smem;                    // [64][76]
    float* r1 = xs + C_*XSW;             // [256][72]
    float* r2 = r1 + H_*R1W;             // [256][68]
    float* r3 = r1;                      // [128][64], aliases r1 (free after conv2)

    const int b   = blockIdx.y;
    const int t0  = blockIdx.x * TT;
    const int tid = threadIdx.x;         // 512 threads

    // ---------------- load x tile (+ halo), zero-fill t<0 / t>=T ----------------
    for (int e = tid; e < C_*XSW; e += 512) {
        const int c  = e / XSW;
        const int tt = e - c*XSW;
        const int t  = t0 - 7 + tt;
        float v = 0.f;
        if (t >= 0 && t < T_) v = x[((size_t)b*C_ + c)*T_ + t];
        smem[e] = v;
    }
    __syncthreads();

    // ---------------- conv1: x(64) -> r1(256); rs1[t] taps x[t-3..t-1] ----------
    // r1[h][j] <-> t = t0-4+j ; x tap index in xs row = j + k   (k=0..2)
    {
        const int h    = tid & 255;
        const int half = tid >> 8;       // j-range: half*36 .. half*36+35
        const float* wr = w_in + (size_t)h * (C_*3);
        float acc[36];
        {
            const float bv = b_in[h];
            #pragma unroll
            for (int j = 0; j < 36; ++j) acc[j] = bv;
        }
        float w0n = wr[0], w1n = wr[1], w2n = wr[2];
        for (int c = 0; c < C_; ++c) {
            const float w0 = w0n, w1 = w1n, w2 = w2n;
            if (c + 1 < C_) { const float* wc = wr + (c+1)*3; w0n = wc[0]; w1n = wc[1]; w2n = wc[2]; }
            const float4* row = (const float4*)(xs + c*XSW);   // 19 float4s per row
            float4 v0 = row[half*9];
            #pragma unroll
            for (int jb = 0; jb < 9; ++jb) {
                const float4 v1 = row[half*9 + jb + 1];
                const int a = jb*4;
                acc[a+0] = fmaf(w0, v0.x, fmaf(w1, v0.y, fmaf(w2, v0.z, acc[a+0])));
                acc[a+1] = fmaf(w0, v0.y, fmaf(w1, v0.z, fmaf(w2, v0.w, acc[a+1])));
                acc[a+2] = fmaf(w0, v0.z, fmaf(w1, v0.w, fmaf(w2, v1.x, acc[a+2])));
                acc[a+3] = fmaf(w0, v0.w, fmaf(w1, v1.x, fmaf(w2, v1.y, acc[a+3])));
                v0 = v1;
            }
        }
        // store; force exact zeros for t<0 (reference zero-pads BETWEEN layers)
        float* dst = r1 + (size_t)h*R1W + half*36;
        #pragma unroll
        for (int j = 0; j < 36; ++j) {
            const int t = t0 - 4 + half*36 + j;
            dst[j] = (t >= 0) ? acc[j] : 0.f;
        }
    }
    __syncthreads();

    // ---------------- conv2: r1(256) -> r2(256); rs2[t] taps rs1[t-2..t] --------
    // r2[h][j2] <-> t = t0-2+j2 ; rs1 tap index in r1 row = j2 + k
    {
        const int h    = tid & 255;
        const int half = tid >> 8;
        const float* wr = w_mid + (size_t)h * (H_*3);
        float acc[36];
        {
            const float bv = b_mid[h];
            #pragma unroll
            for (int j = 0; j < 36; ++j) acc[j] = bv;
        }
        float w0n = wr[0], w1n = wr[1], w2n = wr[2];
        for (int c = 0; c < H_; ++c) {
            const float w0 = w0n, w1 = w1n, w2 = w2n;
            if (c + 1 < H_) { const float* wc = wr + (c+1)*3; w0n = wc[0]; w1n = wc[1]; w2n = wc[2]; }
            const float4* row = (const float4*)(r1 + (size_t)c*R1W);  // 18 float4s
            float4 v0 = row[half*9];
            #pragma unroll
            for (int jb = 0; jb < 9; ++jb) {
                const float4 v1 = row[half*9 + jb + 1];   // jb=8 reads past row -> next row, garbage only feeds unstored j2>=68
                const int a = jb*4;
                acc[a+0] = fmaf(w0, v0.x, fmaf(w1, v0.y, fmaf(w2, v0.z, acc[a+0])));
                acc[a+1] = fmaf(w0, v0.y, fmaf(w1, v0.z, fmaf(w2, v0.w, acc[a+1])));
                acc[a+2] = fmaf(w0, v0.z, fmaf(w1, v0.w, fmaf(w2, v1.x, acc[a+2])));
                acc[a+3] = fmaf(w0, v0.w, fmaf(w1, v1.x, fmaf(w2, v1.y, acc[a+3])));
                v0 = v1;
            }
        }
        float* dst = r2 + (size_t)h*R2W;
        #pragma unroll
        for (int j = 0; j < 36; ++j) {
            const int jj = half*36 + j;
            if (jj < R2W) {
                const int t = t0 - 2 + jj;
                dst[jj] = (t >= 0) ? acc[j] : 0.f;
            }
        }
    }
    __syncthreads();

    // ---------------- conv3: r2(256) -> rs3(128); taps rs2[t-2..t] --------------
    // rs3[oc][jt] <-> t = t0+jt ; rs2 tap index in r2 row = jt + k
    {
        const int oc = tid & 127;
        const int q  = tid >> 7;        // jt-range: q*16 .. q*16+15
        const float* wr = w_out + (size_t)oc * (H_*3);
        float acc[16];
        {
            const float bv = b_out[oc];
            #pragma unroll
            for (int j = 0; j < 16; ++j) acc[j] = bv;
        }
        float w0n = wr[0], w1n = wr[1], w2n = wr[2];
        for (int c = 0; c < H_; ++c) {
            const float w0 = w0n, w1 = w1n, w2 = w2n;
            if (c + 1 < H_) { const float* wc = wr + (c+1)*3; w0n = wc[0]; w1n = wc[1]; w2n = wc[2]; }
            const float4* row = (const float4*)(r2 + (size_t)c*R2W);  // 17 float4s
            float4 v0 = row[q*4];
            #pragma unroll
            for (int jb = 0; jb < 4; ++jb) {
                const float4 v1 = row[q*4 + jb + 1];
                const int a = jb*4;
                acc[a+0] = fmaf(w0, v0.x, fmaf(w1, v0.y, fmaf(w2, v0.z, acc[a+0])));
                acc[a+1] = fmaf(w0, v0.y, fmaf(w1, v0.z, fmaf(w2, v0.w, acc[a+1])));
                acc[a+2] = fmaf(w0, v0.z, fmaf(w1, v0.w, fmaf(w2, v1.x, acc[a+2])));
                acc[a+3] = fmaf(w0, v0.w, fmaf(w1, v1.x, fmaf(w2, v1.y, acc[a+3])));
                v0 = v1;
            }
        }
        // r1 region is dead after the conv2->conv3 barrier; reuse as r3[128][64]
        float* dst = r3 + (size_t)oc*64 + q*16;
        #pragma unroll
        for (int j = 0; j < 16; ++j) dst[j] = acc[j];
    }
    __syncthreads();

    // ---------------- epilogue: z = exp(alpha*tanh(log_s)+beta)*x + t -----------
    {
        #pragma unroll
        for (int m = 0; m < 8; ++m) {
            const int e   = tid + m*512;      // 0..4095
            const int cc  = e >> 6;
            const int ttl = e & 63;
            const float ls = r3[(size_t)cc*64 + ttl];
            const float tv = r3[(size_t)(cc+64)*64 + ttl];
            const float xv = xs[(size_t)cc*XSW + 7 + ttl];
            const float lsv = fmaf(alpha[cc], tanhf(ls), beta[cc]);
            const float zv  = fmaf(expf(lsv), xv, tv);
            out[((size_t)b*C_ + cc)*T_ + t0 + ttl] = zv;
        }
    }
}

extern "C" void kernel_launch(void* const* d_in, const int* in_sizes, int n_in,
                              void* d_out, int out_size, void* d_ws, size_t ws_size,
                              hipStream_t stream) {
    const float* x     = (const float*)d_in[0];
    const float* w_in  = (const float*)d_in[1];
    const float* b_in  = (const float*)d_in[2];
    const float* w_mid = (const float*)d_in[3];
    const float* b_mid = (const float*)d_in[4];
    const float* w_out = (const float*)d_in[5];
    const float* b_out = (const float*)d_in[6];
    const float* alpha = (const float*)d_in[7];
    const float* beta  = (const float*)d_in[8];
    float* out = (float*)d_out;

    dim3 grid(T_/TT, B_);   // (128, 32)
    dim3 block(512);
    hipLaunchKernelGGL(arflow_fused, grid, block, 0, stream,
                       x, w_in, b_in, w_mid, b_mid, w_out, b_out, alpha, beta, out);
}

// Round 2
// 271.829 us; speedup vs baseline: 13.0292x; 13.0292x over previous
//
#include <hip/hip_runtime.h>
#include <cmath>

typedef __attribute__((ext_vector_type(8))) short short8;
typedef __attribute__((ext_vector_type(4))) float f32x4;

#define B_   32
#define C_   64
#define T_   8192
#define H_   256
#define TT   128

// LDS geometry (bytes)
#define RS_ROWB 528          // 256ch*2B + 16B pad  (rows land 4 banks apart)
#define XS_ROWB 144          // 64ch*2B + 16B pad
#define RS1_OFF 0            // 146 rows * 528 = 77088
#define RS2_OFF 77088
#define XS_OFF  77088        // xs aliases rs2 region (disjoint lifetimes)
#define LDS_BYTES 154176

// packed-A workspace layout (bytes): frag = ((tap*MT + mt)*KT + ck)*1024
#define A1_SZ 98304          // 3*16*2*64*16
#define A2_SZ 393216         // 3*16*8*64*16
#define A3_SZ 196608         // 3*8*8*64*16
#define AW_TOTAL (A1_SZ + A2_SZ + A3_SZ)

__device__ __forceinline__ unsigned short f2bf(float f) {
    unsigned u = __builtin_bit_cast(unsigned, f);
    u += 0x7fffu + ((u >> 16) & 1u);          // RNE
    return (unsigned short)(u >> 16);
}

// ---- pack fp32 weights -> bf16 MFMA A-fragments in d_ws (runs every launch) ----
__global__ void pack_w(const float* __restrict__ w1, const float* __restrict__ w2,
                       const float* __restrict__ w3, unsigned short* __restrict__ ws)
{
    int id = blockIdx.x * 256 + threadIdx.x;          // frag-lane id, 43008 total
    const float* w; int MT, KT, Cin; unsigned short* dst;
    if (id < 6144)       {             w = w1; MT = 16; KT = 2; Cin = 64;  dst = ws; }
    else if (id < 30720) { id -= 6144; w = w2; MT = 16; KT = 8; Cin = 256; dst = ws + A1_SZ/2; }
    else if (id < 43008) { id -= 30720; w = w3; MT = 8; KT = 8; Cin = 256; dst = ws + (A1_SZ+A2_SZ)/2; }
    else return;
    const int lane = id & 63;
    int f = id >> 6;
    const int kt = f % KT; f /= KT;
    const int mt = f % MT;
    const int tap = f / MT;
    const int h  = mt*16 + (lane & 15);               // A row (out-channel)
    const int c0 = kt*32 + (lane >> 4)*8;             // A k (in-channel), 8 consecutive
    unsigned short* o = dst + (size_t)id * 8;
    #pragma unroll
    for (int j = 0; j < 8; ++j)
        o[j] = f2bf(w[((size_t)(h*Cin + c0 + j))*3 + tap]);
}

__device__ __forceinline__ short8 ldA(const char* base, int frag, int lane) {
    return *(const short8*)(base + ((size_t)frag*64 + lane)*16);
}

__global__ __launch_bounds__(512, 2)
void arflow_mfma(const float* __restrict__ x,
                 const float* __restrict__ b_in, const float* __restrict__ b_mid,
                 const float* __restrict__ b_out,
                 const float* __restrict__ alpha, const float* __restrict__ beta,
                 const char* __restrict__ wpk,
                 float* __restrict__ out)
{
    __shared__ __align__(16) char lds[LDS_BYTES];
    unsigned short* xs = (unsigned short*)(lds + XS_OFF);   // [147 rows][72 ushort]
    char* rs1 = lds + RS1_OFF;    // bf16 [146 rows][528B]; row r <-> time t0-18+r
    char* rs2 = lds + RS2_OFF;    // same geometry

    const char* wA1 = wpk;
    const char* wA2 = wpk + A1_SZ;
    const char* wA3 = wpk + A1_SZ + A2_SZ;

    const int b   = blockIdx.y;
    const int t0  = blockIdx.x * TT;
    const int tid = threadIdx.x;
    const int lane = tid & 63;
    const int wid  = tid >> 6;
    const int l15 = lane & 15, l4 = lane >> 4;

    // ---------------- stage x -> xs bf16 (row r <-> time t0-19+r) ----------------
    {
        const int tt = tid & 127, cg = tid >> 7;
        for (int p = 0; p < 16; ++p) {
            const int c = cg*16 + p;
            const float* xc = x + ((size_t)b*C_ + c)*T_;
            for (int r = tt; r < 147; r += 128) {
                const int t = t0 - 19 + r;
                float v = (t >= 0) ? xc[t] : 0.f;
                xs[r*72 + c] = f2bf(v);
            }
        }
        if (tid < 264) ((unsigned*)rs1)[tid] = 0u;   // zero rs1 rows 0,1 (halo)
    }
    __syncthreads();

    // ---- conv1: xs(64) -> rs1(256).  N-tiles n=0..8 at times t0-16+16n. K=6 (3 taps x 2) ----
    {
        const int mg = wid >> 1, ng = wid & 1;
        const int ntb = ng ? 5 : 0, nlim = ng ? 4 : 5;
        f32x4 acc[4][5];
        #pragma unroll
        for (int m = 0; m < 4; ++m) {
            const f32x4 bv = *(const f32x4*)(b_in + (mg*4+m)*16 + l4*4);
            #pragma unroll
            for (int nt = 0; nt < 5; ++nt) acc[m][nt] = bv;
        }
        int nb[5];
        #pragma unroll
        for (int nt = 0; nt < 5; ++nt)
            nb[nt] = XS_OFF + (l15 + (ntb+nt)*16)*XS_ROWB + l4*16;   // + tap*144 + ck*64
        short8 Ab[2][4];
        #pragma unroll
        for (int m = 0; m < 4; ++m) Ab[0][m] = ldA(wA1, (mg*4+m)*2, lane);
        #pragma unroll
        for (int kt = 0; kt < 6; ++kt) {
            const int cur = kt & 1;
            const int tap = kt >> 1, ck = kt & 1;
            if (kt < 5) {
                const int kn = kt+1, tapn = kn>>1, ckn = kn&1;
                #pragma unroll
                for (int m = 0; m < 4; ++m)
                    Ab[cur^1][m] = ldA(wA1, (tapn*16 + mg*4+m)*2 + ckn, lane);
            }
            #pragma unroll
            for (int nt = 0; nt < 5; ++nt) if (nt < nlim) {
                const short8 Bf = *(const short8*)(lds + nb[nt] + tap*XS_ROWB + ck*64);
                #pragma unroll
                for (int m = 0; m < 4; ++m)
                    acc[m][nt] = __builtin_amdgcn_mfma_f32_16x16x32_bf16(Ab[cur][m], Bf, acc[m][nt], 0, 0, 0);
            }
        }
        #pragma unroll
        for (int nt = 0; nt < 5; ++nt) if (nt < nlim) {
            const int tcol = t0 - 16 + (ntb+nt)*16 + l15;
            char* dst0 = rs1 + (2 + (ntb+nt)*16 + l15)*RS_ROWB;
            #pragma unroll
            for (int m = 0; m < 4; ++m) {
                const f32x4 a = acc[m][nt];
                unsigned long long pk = 0ull;
                if (tcol >= 0)
                    pk = (unsigned long long)(f2bf(a.x) | ((unsigned)f2bf(a.y) << 16))
                       | ((unsigned long long)(f2bf(a.z) | ((unsigned)f2bf(a.w) << 16)) << 32);
                *(unsigned long long*)(dst0 + ((mg*4+m)*16 + l4*4)*2) = pk;   // 4 ch @ one time
            }
        }
    }
    __syncthreads();

    // ---- conv2: rs1(256) -> rs2(256). K=24 (3 taps x 8). B row = 16n + l15 + tap ----
    {
        const int mg = wid >> 1, ng = wid & 1;
        const int ntb = ng ? 5 : 0, nlim = ng ? 4 : 5;
        f32x4 acc[4][5];
        #pragma unroll
        for (int m = 0; m < 4; ++m) {
            const f32x4 bv = *(const f32x4*)(b_mid + (mg*4+m)*16 + l4*4);
            #pragma unroll
            for (int nt = 0; nt < 5; ++nt) acc[m][nt] = bv;
        }
        int nb[5];
        #pragma unroll
        for (int nt = 0; nt < 5; ++nt)
            nb[nt] = RS1_OFF + (l15 + (ntb+nt)*16)*RS_ROWB + l4*16;
        short8 Ab[2][4];
        #pragma unroll
        for (int m = 0; m < 4; ++m) Ab[0][m] = ldA(wA2, (mg*4+m)*8, lane);
        #pragma unroll
        for (int kt = 0; kt < 24; ++kt) {
            const int cur = kt & 1;
            const int tap = kt >> 3, ck = kt & 7;
            if (kt < 23) {
                const int kn = kt+1, tapn = kn>>3, ckn = kn&7;
                #pragma unroll
                for (int m = 0; m < 4; ++m)
                    Ab[cur^1][m] = ldA(wA2, (tapn*16 + mg*4+m)*8 + ckn, lane);
            }
            #pragma unroll
            for (int nt = 0; nt < 5; ++nt) if (nt < nlim) {
                const short8 Bf = *(const short8*)(lds + nb[nt] + tap*RS_ROWB + ck*64);
                #pragma unroll
                for (int m = 0; m < 4; ++m)
                    acc[m][nt] = __builtin_amdgcn_mfma_f32_16x16x32_bf16(Ab[cur][m], Bf, acc[m][nt], 0, 0, 0);
            }
        }
        #pragma unroll
        for (int nt = 0; nt < 5; ++nt) if (nt < nlim) {
            const int tcol = t0 - 16 + (ntb+nt)*16 + l15;
            char* dst0 = rs2 + (2 + (ntb+nt)*16 + l15)*RS_ROWB;
            #pragma unroll
            for (int m = 0; m < 4; ++m) {
                const f32x4 a = acc[m][nt];
                unsigned long long pk = 0ull;
                if (tcol >= 0)
                    pk = (unsigned long long)(f2bf(a.x) | ((unsigned)f2bf(a.y) << 16))
                       | ((unsigned long long)(f2bf(a.z) | ((unsigned)f2bf(a.w) << 16)) << 32);
                *(unsigned long long*)(dst0 + ((mg*4+m)*16 + l4*4)*2) = pk;
            }
        }
    }
    __syncthreads();

    // ---- conv3: rs2(256) -> rs3(128, fp32 in rs1 region). N: 8 tiles at t0+16n ----
    {
        const int mg = wid >> 2;          // 0..1 -> mtiles mg*4+m  (M=128)
        const int ng = wid & 3;           // 0..3 -> 2 ntiles each
        const int ntb = ng * 2;
        f32x4 acc[4][2];
        #pragma unroll
        for (int m = 0; m < 4; ++m) {
            const f32x4 bv = *(const f32x4*)(b_out + (mg*4+m)*16 + l4*4);
            acc[m][0] = bv; acc[m][1] = bv;
        }
        int nb[2];
        #pragma unroll
        for (int nt = 0; nt < 2; ++nt)
            nb[nt] = RS2_OFF + (16 + (ntb+nt)*16 + l15)*RS_ROWB + l4*16;  // row = 16n+l15+16+tap
        short8 Ab[2][4];
        #pragma unroll
        for (int m = 0; m < 4; ++m) Ab[0][m] = ldA(wA3, (mg*4+m)*8, lane);
        #pragma unroll
        for (int kt = 0; kt < 24; ++kt) {
            const int cur = kt & 1;
            const int tap = kt >> 3, ck = kt & 7;
            if (kt < 23) {
                const int kn = kt+1, tapn = kn>>3, ckn = kn&7;
                #pragma unroll
                for (int m = 0; m < 4; ++m)
                    Ab[cur^1][m] = ldA(wA3, (tapn*8 + mg*4+m)*8 + ckn, lane);
            }
            #pragma unroll
            for (int nt = 0; nt < 2; ++nt) {
                const short8 Bf = *(const short8*)(lds + nb[nt] + tap*RS_ROWB + ck*64);
                #pragma unroll
                for (int m = 0; m < 4; ++m)
                    acc[m][nt] = __builtin_amdgcn_mfma_f32_16x16x32_bf16(Ab[cur][m], Bf, acc[m][nt], 0, 0, 0);
            }
        }
        #pragma unroll
        for (int nt = 0; nt < 2; ++nt) {
            char* dst0 = lds + RS1_OFF + ((ntb+nt)*16 + l15)*RS_ROWB;    // fp32 rows, stride 528
            #pragma unroll
            for (int m = 0; m < 4; ++m)
                *(f32x4*)(dst0 + ((mg*4+m)*16 + l4*4)*4) = acc[m][nt];
        }
    }
    __syncthreads();

    // ---- epilogue: z = exp(alpha*tanh(log_s)+beta)*x + t ----
    {
        const float* rs3f = (const float*)(lds + RS1_OFF);   // [t][132 floats]
        #pragma unroll
        for (int m = 0; m < 16; ++m) {
            const int e = tid + m*512;            // 8192 = 64c * 128t
            const int c = e >> 7, t = e & 127;
            const float ls = rs3f[t*132 + c];
            const float tv = rs3f[t*132 + c + 64];
            const float xv = x[((size_t)b*C_ + c)*T_ + t0 + t];
            const float lsv = fmaf(alpha[c], tanhf(ls), beta[c]);
            out[((size_t)b*C_ + c)*T_ + t0 + t] = fmaf(__expf(lsv), xv, tv);
        }
    }
}

extern "C" void kernel_launch(void* const* d_in, const int* in_sizes, int n_in,
                              void* d_out, int out_size, void* d_ws, size_t ws_size,
                              hipStream_t stream) {
    const float* x     = (const float*)d_in[0];
    const float* w_in  = (const float*)d_in[1];
    const float* b_in  = (const float*)d_in[2];
    const float* w_mid = (const float*)d_in[3];
    const float* b_mid = (const float*)d_in[4];
    const float* w_out = (const float*)d_in[5];
    const float* b_out = (const float*)d_in[6];
    const float* alpha = (const float*)d_in[7];
    const float* beta  = (const float*)d_in[8];
    float* out = (float*)d_out;

    if (ws_size < (size_t)AW_TOTAL) return;   // visible failure if ws too small

    hipLaunchKernelGGL(pack_w, dim3(168), dim3(256), 0, stream,
                       w_in, w_mid, w_out, (unsigned short*)d_ws);
    hipLaunchKernelGGL(arflow_mfma, dim3(T_/TT, B_), dim3(512), 0, stream,
                       x, b_in, b_mid, b_out, alpha, beta, (const char*)d_ws, out);
}

// Round 4
// 255.190 us; speedup vs baseline: 13.8787x; 1.0652x over previous
//
#include <hip/hip_runtime.h>
#include <cmath>

typedef __attribute__((ext_vector_type(8))) short short8;
typedef __attribute__((ext_vector_type(4))) float f32x4;

#define B_   32
#define C_   64
#define T_   8192
#define H_   256
#define TT   64

// LDS geometry (bytes). Row r of rs1 <-> time t0-18+r; row r of rs2 <-> t0-2+r.
#define XS_ROWB 144          // 64ch*2B + 16B pad
#define RS_ROWB 528          // 256ch*2B + 16B pad
#define RS1_OFF 0            // 82 rows * 528 = 43296
#define RS2_OFF 43296        // 66 rows * 528 = 34848
#define XS_OFF  43296        // xs [83 rows][144B] aliases rs2 (disjoint lifetimes)
#define RS3_OFF 0            // rs3 fp32 [64 rows][528B] aliases rs1 (dead after conv2)
#define LDS_BYTES 78144      // 2 blocks/CU (156.3 KB of 160 KB)

// packed-A workspace (bytes): frag = ((tap*MT + mt)*KT + ck) * 1024
#define A1_SZ 98304          // 3*16*2 frags
#define A2_SZ 393216         // 3*16*8
#define A3_SZ 196608         // 3*8*8
#define AW_TOTAL (A1_SZ + A2_SZ + A3_SZ)

__device__ __forceinline__ unsigned short f2bf(float f) {
    unsigned u = __builtin_bit_cast(unsigned, f);
    u += 0x7fffu + ((u >> 16) & 1u);          // RNE
    return (unsigned short)(u >> 16);
}

// HW packed f32->bf16 (RNE): low16 = bf16(lo), high16 = bf16(hi)
__device__ __forceinline__ unsigned cvtpk(float lo, float hi) {
    unsigned r;
    asm("v_cvt_pk_bf16_f32 %0, %1, %2" : "=v"(r) : "v"(lo), "v"(hi));
    return r;
}

// ---- pack fp32 weights -> bf16 MFMA A-fragments in d_ws ----
__global__ void pack_w(const float* __restrict__ w1, const float* __restrict__ w2,
                       const float* __restrict__ w3, unsigned short* __restrict__ ws)
{
    int id = blockIdx.x * 256 + threadIdx.x;          // frag-lane id, 43008 total
    const float* w; int MT, KT, Cin; unsigned short* dst;
    if (id < 6144)       {             w = w1; MT = 16; KT = 2; Cin = 64;  dst = ws; }
    else if (id < 30720) { id -= 6144; w = w2; MT = 16; KT = 8; Cin = 256; dst = ws + A1_SZ/2; }
    else if (id < 43008) { id -= 30720; w = w3; MT = 8; KT = 8; Cin = 256; dst = ws + (A1_SZ+A2_SZ)/2; }
    else return;
    const int lane = id & 63;
    int f = id >> 6;
    const int kt = f % KT; f /= KT;
    const int mt = f % MT;
    const int tap = f / MT;
    const int h  = mt*16 + (lane & 15);               // A row (out-channel)
    const int c0 = kt*32 + (lane >> 4)*8;             // A k (in-channel), 8 consecutive
    unsigned short* o = dst + (size_t)id * 8;
    #pragma unroll
    for (int j = 0; j < 8; ++j)
        o[j] = f2bf(w[((size_t)(h*Cin + c0 + j))*3 + tap]);
}

__device__ __forceinline__ short8 ldA(const char* base, int frag, int lane) {
    return *(const short8*)(base + ((size_t)frag*64 + lane)*16);
}

__global__ __launch_bounds__(512, 4)
void arflow_mfma(const float* __restrict__ x,
                 const float* __restrict__ b_in, const float* __restrict__ b_mid,
                 const float* __restrict__ b_out,
                 const float* __restrict__ alpha, const float* __restrict__ beta,
                 const char* __restrict__ wpk,
                 float* __restrict__ out)
{
    __shared__ __align__(16) char lds[LDS_BYTES];
    unsigned short* xs = (unsigned short*)(lds + XS_OFF);   // [83 rows][72 ushort], row r <-> t0-19+r
    char* rs1 = lds + RS1_OFF;
    char* rs2 = lds + RS2_OFF;

    const char* wA1 = wpk;
    const char* wA2 = wpk + A1_SZ;
    const char* wA3 = wpk + A1_SZ + A2_SZ;

    const int b   = blockIdx.y;
    const int t0  = blockIdx.x * TT;
    const int tid = threadIdx.x;
    const int lane = tid & 63;
    const int wid  = tid >> 6;
    const int l15 = lane & 15, l4 = lane >> 4;

    // ---------------- stage x -> xs bf16; zero rs1 halo rows 0,1 ----------------
    {
        const int rr = tid & 63, cg = tid >> 6;
        #pragma unroll
        for (int p = 0; p < 4; ++p) {
            const int c = cg*8 + p*2;
            const float* xc0 = x + ((size_t)b*C_ + c)*T_;
            const float* xc1 = xc0 + T_;
            {
                const int r = rr; const int t = t0 - 19 + r;
                float v0 = 0.f, v1 = 0.f;
                if (t >= 0) { v0 = xc0[t]; v1 = xc1[t]; }
                *(unsigned*)(&xs[r*72 + c]) = cvtpk(v0, v1);
            }
            {
                const int r = rr + 64;
                if (r < 83) {
                    const int t = t0 - 19 + r;   // always in [45, 8191]
                    *(unsigned*)(&xs[r*72 + c]) = cvtpk(xc0[t], xc1[t]);
                }
            }
        }
        if (tid < 264) ((unsigned*)rs1)[tid] = 0u;   // rows 0,1 (t0-18,t0-17) = 0
    }
    __syncthreads();

    // ---- conv1: xs(64) -> rs1(256). N-tiles at t0-16+16n, n=0..4. K=6 (3 taps x 2) ----
    {
        const int mg = wid >> 1, ng = wid & 1;
        const int ntb = ng ? 3 : 0, ncnt = ng ? 2 : 3;
        f32x4 acc[4][3];
        #pragma unroll
        for (int m = 0; m < 4; ++m) {
            const f32x4 bv = *(const f32x4*)(b_in + (mg*4+m)*16 + l4*4);
            #pragma unroll
            for (int nt = 0; nt < 3; ++nt) acc[m][nt] = bv;
        }
        int nb[3];
        #pragma unroll
        for (int nt = 0; nt < 3; ++nt)
            nb[nt] = XS_OFF + (16*(ntb+nt) + l15)*XS_ROWB + l4*16;
        short8 Ab[2][4];
        #pragma unroll
        for (int m = 0; m < 4; ++m) Ab[0][m] = ldA(wA1, (mg*4+m)*2, lane);
        #pragma unroll
        for (int kt = 0; kt < 6; ++kt) {
            const int cur = kt & 1;
            const int tap = kt >> 1, ck = kt & 1;
            if (kt < 5) {
                const int kn = kt+1, tapn = kn>>1, ckn = kn&1;
                #pragma unroll
                for (int m = 0; m < 4; ++m)
                    Ab[cur^1][m] = ldA(wA1, (tapn*16 + mg*4+m)*2 + ckn, lane);
            }
            __builtin_amdgcn_s_setprio(1);
            #pragma unroll
            for (int nt = 0; nt < 3; ++nt) if (nt < ncnt) {
                const short8 Bf = *(const short8*)(lds + nb[nt] + tap*XS_ROWB + ck*64);
                #pragma unroll
                for (int m = 0; m < 4; ++m)
                    acc[m][nt] = __builtin_amdgcn_mfma_f32_16x16x32_bf16(Ab[cur][m], Bf, acc[m][nt], 0, 0, 0);
            }
            __builtin_amdgcn_s_setprio(0);
        }
        #pragma unroll
        for (int nt = 0; nt < 3; ++nt) if (nt < ncnt) {
            const int tt16 = 16*(ntb+nt) + l15;
            const int t = t0 - 16 + tt16;
            char* dst0 = rs1 + (2 + tt16)*RS_ROWB;
            #pragma unroll
            for (int m = 0; m < 4; ++m) {
                const f32x4 a = acc[m][nt];
                unsigned long long pk = 0ull;
                if (t >= 0)
                    pk = (unsigned long long)cvtpk(a.x, a.y)
                       | ((unsigned long long)cvtpk(a.z, a.w) << 32);
                *(unsigned long long*)(dst0 + ((mg*4+m)*16 + l4*4)*2) = pk;
            }
        }
    }
    __syncthreads();

    // ---- conv2: rs1(256) -> rs2(256). K=24. Store only rows t >= t0-2 ----
    {
        const int mg = wid >> 1, ng = wid & 1;
        const int ntb = ng ? 3 : 0, ncnt = ng ? 2 : 3;
        f32x4 acc[4][3];
        #pragma unroll
        for (int m = 0; m < 4; ++m) {
            const f32x4 bv = *(const f32x4*)(b_mid + (mg*4+m)*16 + l4*4);
            #pragma unroll
            for (int nt = 0; nt < 3; ++nt) acc[m][nt] = bv;
        }
        int nb[3];
        #pragma unroll
        for (int nt = 0; nt < 3; ++nt)
            nb[nt] = RS1_OFF + (16*(ntb+nt) + l15)*RS_ROWB + l4*16;
        short8 Ab[2][4];
        #pragma unroll
        for (int m = 0; m < 4; ++m) Ab[0][m] = ldA(wA2, (mg*4+m)*8, lane);
        #pragma unroll
        for (int kt = 0; kt < 24; ++kt) {
            const int cur = kt & 1;
            const int tap = kt >> 3, ck = kt & 7;
            if (kt < 23) {
                const int kn = kt+1, tapn = kn>>3, ckn = kn&7;
                #pragma unroll
                for (int m = 0; m < 4; ++m)
                    Ab[cur^1][m] = ldA(wA2, (tapn*16 + mg*4+m)*8 + ckn, lane);
            }
            __builtin_amdgcn_s_setprio(1);
            #pragma unroll
            for (int nt = 0; nt < 3; ++nt) if (nt < ncnt) {
                const short8 Bf = *(const short8*)(lds + nb[nt] + tap*RS_ROWB + ck*64);
                #pragma unroll
                for (int m = 0; m < 4; ++m)
                    acc[m][nt] = __builtin_amdgcn_mfma_f32_16x16x32_bf16(Ab[cur][m], Bf, acc[m][nt], 0, 0, 0);
            }
            __builtin_amdgcn_s_setprio(0);
        }
        #pragma unroll
        for (int nt = 0; nt < 3; ++nt) if (nt < ncnt) {
            const int tt16 = 16*(ntb+nt) + l15;
            const int r2row = tt16 - 14;             // rs2 row <-> t0-2+row
            if (r2row >= 0) {
                const int t = t0 - 16 + tt16;
                char* dst0 = rs2 + r2row*RS_ROWB;
                #pragma unroll
                for (int m = 0; m < 4; ++m) {
                    const f32x4 a = acc[m][nt];
                    unsigned long long pk = 0ull;
                    if (t >= 0)
                        pk = (unsigned long long)cvtpk(a.x, a.y)
                           | ((unsigned long long)cvtpk(a.z, a.w) << 32);
                    *(unsigned long long*)(dst0 + ((mg*4+m)*16 + l4*4)*2) = pk;
                }
            }
        }
    }
    __syncthreads();

    // ---- prefetch epilogue x into regs (hides under conv3 MFMA) ----
    float xv[8];
    {
        #pragma unroll
        for (int m = 0; m < 8; ++m) {
            const int e = tid + m*512;               // 4096 = 64c * 64t
            const int c = e >> 6, tl = e & 63;
            xv[m] = x[((size_t)b*C_ + c)*T_ + t0 + tl];
        }
    }

    // ---- conv3: rs2(256) -> rs3(128, fp32). N-tiles at t0+16n, n=0..3 ----
    {
        const int mg = wid >> 2;                     // 0..1 -> 4 mtiles each (M=128)
        const int ng = wid & 3;                      // nt = ng
        f32x4 acc[4];
        #pragma unroll
        for (int m = 0; m < 4; ++m)
            acc[m] = *(const f32x4*)(b_out + (mg*4+m)*16 + l4*4);
        const int nb0 = RS2_OFF + (16*ng + l15)*RS_ROWB + l4*16;
        short8 Ab[2][4];
        #pragma unroll
        for (int m = 0; m < 4; ++m) Ab[0][m] = ldA(wA3, (mg*4+m)*8, lane);
        #pragma unroll
        for (int kt = 0; kt < 24; ++kt) {
            const int cur = kt & 1;
            const int tap = kt >> 3, ck = kt & 7;
            if (kt < 23) {
                const int kn = kt+1, tapn = kn>>3, ckn = kn&7;
                #pragma unroll
                for (int m = 0; m < 4; ++m)
                    Ab[cur^1][m] = ldA(wA3, (tapn*8 + mg*4+m)*8 + ckn, lane);
            }
            const short8 Bf = *(const short8*)(lds + nb0 + tap*RS_ROWB + ck*64);
            __builtin_amdgcn_s_setprio(1);
            #pragma unroll
            for (int m = 0; m < 4; ++m)
                acc[m] = __builtin_amdgcn_mfma_f32_16x16x32_bf16(Ab[cur][m], Bf, acc[m], 0, 0, 0);
            __builtin_amdgcn_s_setprio(0);
        }
        char* dst0 = lds + RS3_OFF + (16*ng + l15)*RS_ROWB;   // fp32 rows [64][132f]
        #pragma unroll
        for (int m = 0; m < 4; ++m)
            *(f32x4*)(dst0 + ((mg*4+m)*16 + l4*4)*4) = acc[m];
    }
    __syncthreads();

    // ---- epilogue: z = exp(alpha*tanh(log_s)+beta)*x + t ----
    {
        const float* rs3f = (const float*)(lds + RS3_OFF);
        #pragma unroll
        for (int m = 0; m < 8; ++m) {
            const int e = tid + m*512;
            const int c = e >> 6, tl = e & 63;
            const float ls = rs3f[tl*132 + c];
            const float tv = rs3f[tl*132 + c + 64];
            // tanh(ls) = 1 - 2/(exp(2*ls)+1)  (saturates correctly at +-inf)
            const float e2 = __expf(2.f * ls);
            const float th = fmaf(-2.f, __builtin_amdgcn_rcpf(e2 + 1.f), 1.f);
            const float lsv = fmaf(alpha[c], th, beta[c]);
            out[((size_t)b*C_ + c)*T_ + t0 + tl] = fmaf(__expf(lsv), xv[m], tv);
        }
    }
}

extern "C" void kernel_launch(void* const* d_in, const int* in_sizes, int n_in,
                              void* d_out, int out_size, void* d_ws, size_t ws_size,
                              hipStream_t stream) {
    const float* x     = (const float*)d_in[0];
    const float* w_in  = (const float*)d_in[1];
    const float* b_in  = (const float*)d_in[2];
    const float* w_mid = (const float*)d_in[3];
    const float* b_mid = (const float*)d_in[4];
    const float* w_out = (const float*)d_in[5];
    const float* b_out = (const float*)d_in[6];
    const float* alpha = (const float*)d_in[7];
    const float* beta  = (const float*)d_in[8];
    float* out = (float*)d_out;

    if (ws_size < (size_t)AW_TOTAL) return;

    hipLaunchKernelGGL(pack_w, dim3(168), dim3(256), 0, stream,
                       w_in, w_mid, w_out, (unsigned short*)d_ws);
    hipLaunchKernelGGL(arflow_mfma, dim3(T_/TT, B_), dim3(512), 0, stream,
                       x, b_in, b_mid, b_out, alpha, beta, (const char*)d_ws, out);
}

// Round 5
// 215.506 us; speedup vs baseline: 16.4343x; 1.1841x over previous
//
#include <hip/hip_runtime.h>
#include <cmath>

typedef __attribute__((ext_vector_type(8))) short short8;
typedef __attribute__((ext_vector_type(4))) float f32x4;

#define B_   32
#define C_   64
#define T_   8192
#define H_   256
#define TT   64

// LDS geometry (bytes). Row r of rs1 <-> time t0-18+r; row r of rs2 <-> t0-2+r.
#define XS_ROWB 144          // 64ch*2B + 16B pad
#define RS_ROWB 528          // 256ch*2B + 16B pad
#define RS1_OFF 0            // 82 rows * 528 = 43296
#define RS2_OFF 43296        // 66 rows * 528 = 34848
#define XS_OFF  43296        // xs [83 rows][144B] aliases rs2 (disjoint lifetimes)
#define RS3_OFF 0            // rs3 fp32 [64 rows][528B] aliases rs1 (dead after conv2)
#define LDS_BYTES 78144      // 2 blocks/CU (156.3 KB of 160 KB)

// packed-A workspace (bytes): frag = ((tap*MT + mt)*KT + ck) * 1024
#define A1_SZ 98304          // 3*16*2 frags
#define A2_SZ 393216         // 3*16*8
#define A3_SZ 196608         // 3*8*8
#define AW_TOTAL (A1_SZ + A2_SZ + A3_SZ)

__device__ __forceinline__ unsigned short f2bf(float f) {
    unsigned u = __builtin_bit_cast(unsigned, f);
    u += 0x7fffu + ((u >> 16) & 1u);          // RNE
    return (unsigned short)(u >> 16);
}

// HW packed f32->bf16 (RNE): low16 = bf16(lo), high16 = bf16(hi)
__device__ __forceinline__ unsigned cvtpk(float lo, float hi) {
    unsigned r;
    asm("v_cvt_pk_bf16_f32 %0, %1, %2" : "=v"(r) : "v"(lo), "v"(hi));
    return r;
}

// ---- pack fp32 weights -> bf16 MFMA A-fragments in d_ws ----
__global__ void pack_w(const float* __restrict__ w1, const float* __restrict__ w2,
                       const float* __restrict__ w3, unsigned short* __restrict__ ws)
{
    int id = blockIdx.x * 256 + threadIdx.x;          // frag-lane id, 43008 total
    const float* w; int MT, KT, Cin; unsigned short* dst;
    if (id < 6144)       {             w = w1; MT = 16; KT = 2; Cin = 64;  dst = ws; }
    else if (id < 30720) { id -= 6144; w = w2; MT = 16; KT = 8; Cin = 256; dst = ws + A1_SZ/2; }
    else if (id < 43008) { id -= 30720; w = w3; MT = 8; KT = 8; Cin = 256; dst = ws + (A1_SZ+A2_SZ)/2; }
    else return;
    const int lane = id & 63;
    int f = id >> 6;
    const int kt = f % KT; f /= KT;
    const int mt = f % MT;
    const int tap = f / MT;
    const int h  = mt*16 + (lane & 15);               // A row (out-channel)
    const int c0 = kt*32 + (lane >> 4)*8;             // A k (in-channel), 8 consecutive
    unsigned short* o = dst + (size_t)id * 8;
    #pragma unroll
    for (int j = 0; j < 8; ++j)
        o[j] = f2bf(w[((size_t)(h*Cin + c0 + j))*3 + tap]);
}

__device__ __forceinline__ short8 ldA(const char* base, int frag, int lane) {
    return *(const short8*)(base + ((size_t)frag*64 + lane)*16);
}

__global__ __launch_bounds__(512, 4)
void arflow_mfma(const float* __restrict__ x,
                 const float* __restrict__ b_in, const float* __restrict__ b_mid,
                 const float* __restrict__ b_out,
                 const float* __restrict__ alpha, const float* __restrict__ beta,
                 const char* __restrict__ wpk,
                 float* __restrict__ out)
{
    __shared__ __align__(16) char lds[LDS_BYTES];
    unsigned short* xs = (unsigned short*)(lds + XS_OFF);   // [83 rows][72 ushort], row r <-> t0-19+r
    char* rs1 = lds + RS1_OFF;
    char* rs2 = lds + RS2_OFF;

    const char* wA1 = wpk;
    const char* wA2 = wpk + A1_SZ;
    const char* wA3 = wpk + A1_SZ + A2_SZ;

    const int b   = blockIdx.y;
    const int t0  = blockIdx.x * TT;
    const int tid = threadIdx.x;
    const int lane = tid & 63;
    const int wid  = tid >> 6;
    const int l15 = lane & 15, l4 = lane >> 4;

    // ---------------- stage x -> xs bf16; zero rs1 halo rows 0,1 ----------------
    {
        const int rr = tid & 63, cg = tid >> 6;
        #pragma unroll
        for (int p = 0; p < 4; ++p) {
            const int c = cg*8 + p*2;
            const float* xc0 = x + ((size_t)b*C_ + c)*T_;
            const float* xc1 = xc0 + T_;
            {
                const int r = rr; const int t = t0 - 19 + r;
                float v0 = 0.f, v1 = 0.f;
                if (t >= 0) { v0 = xc0[t]; v1 = xc1[t]; }
                *(unsigned*)(&xs[r*72 + c]) = cvtpk(v0, v1);
            }
            {
                const int r = rr + 64;
                if (r < 83) {
                    const int t = t0 - 19 + r;   // always in [45, 8191]
                    *(unsigned*)(&xs[r*72 + c]) = cvtpk(xc0[t], xc1[t]);
                }
            }
        }
        if (tid < 264) ((unsigned*)rs1)[tid] = 0u;   // rows 0,1 (t0-18,t0-17) = 0
    }
    __syncthreads();

    // ---- conv1: xs(64) -> rs1(256). Wave wid owns mtiles {2wid,2wid+1} x ALL 5 ntiles.
    //      A1 read exactly once per block. K=6 (3 taps x 2 ck) ----
    {
        const int mt0 = wid*2;
        f32x4 acc[2][5];
        #pragma unroll
        for (int m = 0; m < 2; ++m) {
            const f32x4 bv = *(const f32x4*)(b_in + (mt0+m)*16 + l4*4);
            #pragma unroll
            for (int nt = 0; nt < 5; ++nt) acc[m][nt] = bv;
        }
        int nb[5];
        #pragma unroll
        for (int nt = 0; nt < 5; ++nt)
            nb[nt] = XS_OFF + (16*nt + l15)*XS_ROWB + l4*16;
        short8 Ab[2][2];
        #pragma unroll
        for (int m = 0; m < 2; ++m) Ab[0][m] = ldA(wA1, (mt0+m)*2, lane);
        #pragma unroll
        for (int kt = 0; kt < 6; ++kt) {
            const int cur = kt & 1;
            const int tap = kt >> 1, ck = kt & 1;
            if (kt < 5) {
                const int kn = kt+1, tapn = kn>>1, ckn = kn&1;
                #pragma unroll
                for (int m = 0; m < 2; ++m)
                    Ab[cur^1][m] = ldA(wA1, (tapn*16 + mt0+m)*2 + ckn, lane);
            }
            __builtin_amdgcn_s_setprio(1);
            #pragma unroll
            for (int nt = 0; nt < 5; ++nt) {
                const short8 Bf = *(const short8*)(lds + nb[nt] + tap*XS_ROWB + ck*64);
                #pragma unroll
                for (int m = 0; m < 2; ++m)
                    acc[m][nt] = __builtin_amdgcn_mfma_f32_16x16x32_bf16(Ab[cur][m], Bf, acc[m][nt], 0, 0, 0);
            }
            __builtin_amdgcn_s_setprio(0);
        }
        #pragma unroll
        for (int nt = 0; nt < 5; ++nt) {
            const int tt16 = 16*nt + l15;
            const int t = t0 - 16 + tt16;
            char* dst0 = rs1 + (2 + tt16)*RS_ROWB;
            #pragma unroll
            for (int m = 0; m < 2; ++m) {
                const f32x4 a = acc[m][nt];
                unsigned long long pk = 0ull;
                if (t >= 0)
                    pk = (unsigned long long)cvtpk(a.x, a.y)
                       | ((unsigned long long)cvtpk(a.z, a.w) << 32);
                *(unsigned long long*)(dst0 + ((mt0+m)*16 + l4*4)*2) = pk;
            }
        }
    }
    __syncthreads();

    // ---- conv2: rs1(256) -> rs2(256). Wm=4/Wn=2 (balanced). K=24 ----
    {
        const int mg = wid >> 1, ng = wid & 1;
        const int ntb = ng ? 3 : 0, ncnt = ng ? 2 : 3;
        f32x4 acc[4][3];
        #pragma unroll
        for (int m = 0; m < 4; ++m) {
            const f32x4 bv = *(const f32x4*)(b_mid + (mg*4+m)*16 + l4*4);
            #pragma unroll
            for (int nt = 0; nt < 3; ++nt) acc[m][nt] = bv;
        }
        int nb[3];
        #pragma unroll
        for (int nt = 0; nt < 3; ++nt)
            nb[nt] = RS1_OFF + (16*(ntb+nt) + l15)*RS_ROWB + l4*16;
        short8 Ab[2][4];
        #pragma unroll
        for (int m = 0; m < 4; ++m) Ab[0][m] = ldA(wA2, (mg*4+m)*8, lane);
        #pragma unroll
        for (int kt = 0; kt < 24; ++kt) {
            const int cur = kt & 1;
            const int tap = kt >> 3, ck = kt & 7;
            if (kt < 23) {
                const int kn = kt+1, tapn = kn>>3, ckn = kn&7;
                #pragma unroll
                for (int m = 0; m < 4; ++m)
                    Ab[cur^1][m] = ldA(wA2, (tapn*16 + mg*4+m)*8 + ckn, lane);
            }
            __builtin_amdgcn_s_setprio(1);
            #pragma unroll
            for (int nt = 0; nt < 3; ++nt) if (nt < ncnt) {
                const short8 Bf = *(const short8*)(lds + nb[nt] + tap*RS_ROWB + ck*64);
                #pragma unroll
                for (int m = 0; m < 4; ++m)
                    acc[m][nt] = __builtin_amdgcn_mfma_f32_16x16x32_bf16(Ab[cur][m], Bf, acc[m][nt], 0, 0, 0);
            }
            __builtin_amdgcn_s_setprio(0);
        }
        #pragma unroll
        for (int nt = 0; nt < 3; ++nt) if (nt < ncnt) {
            const int tt16 = 16*(ntb+nt) + l15;
            const int r2row = tt16 - 14;             // rs2 row <-> t0-2+row
            if (r2row >= 0) {
                const int t = t0 - 16 + tt16;
                char* dst0 = rs2 + r2row*RS_ROWB;
                #pragma unroll
                for (int m = 0; m < 4; ++m) {
                    const f32x4 a = acc[m][nt];
                    unsigned long long pk = 0ull;
                    if (t >= 0)
                        pk = (unsigned long long)cvtpk(a.x, a.y)
                           | ((unsigned long long)cvtpk(a.z, a.w) << 32);
                    *(unsigned long long*)(dst0 + ((mg*4+m)*16 + l4*4)*2) = pk;
                }
            }
        }
    }
    __syncthreads();

    // ---- prefetch epilogue x into regs (hides under conv3 MFMA) ----
    float xv[8];
    {
        #pragma unroll
        for (int m = 0; m < 8; ++m) {
            const int e = tid + m*512;               // 4096 = 64c * 64t
            const int c = e >> 6, tl = e & 63;
            xv[m] = x[((size_t)b*C_ + c)*T_ + t0 + tl];
        }
    }

    // ---- conv3: rs2(256) -> rs3(128, fp32). Wave wid owns mtile wid x ALL 4 ntiles.
    //      A3 read exactly once per block (was 4x). 2-deep A prefetch ----
    {
        const int mt = wid;                          // 0..7 (M=128)
        f32x4 acc[4];
        {
            const f32x4 bv = *(const f32x4*)(b_out + mt*16 + l4*4);
            #pragma unroll
            for (int nt = 0; nt < 4; ++nt) acc[nt] = bv;
        }
        int nb[4];
        #pragma unroll
        for (int nt = 0; nt < 4; ++nt)
            nb[nt] = RS2_OFF + (16*nt + l15)*RS_ROWB + l4*16;
        short8 Ab[2];
        Ab[0] = ldA(wA3, mt*8 + 0, lane);            // kt=0: tap0,ck0
        Ab[1] = ldA(wA3, mt*8 + 1, lane);            // kt=1: tap0,ck1
        #pragma unroll
        for (int kt = 0; kt < 24; ++kt) {
            const int cur = kt & 1;
            const int tap = kt >> 3, ck = kt & 7;
            __builtin_amdgcn_s_setprio(1);
            #pragma unroll
            for (int nt = 0; nt < 4; ++nt) {
                const short8 Bf = *(const short8*)(lds + nb[nt] + tap*RS_ROWB + ck*64);
                acc[nt] = __builtin_amdgcn_mfma_f32_16x16x32_bf16(Ab[cur], Bf, acc[nt], 0, 0, 0);
            }
            __builtin_amdgcn_s_setprio(0);
            if (kt + 2 < 24) {
                const int kn = kt+2, tapn = kn>>3, ckn = kn&7;
                Ab[cur] = ldA(wA3, (tapn*8 + mt)*8 + ckn, lane);
            }
        }
        #pragma unroll
        for (int nt = 0; nt < 4; ++nt) {
            char* dst0 = lds + RS3_OFF + (16*nt + l15)*RS_ROWB;   // fp32 rows [64][132f]
            *(f32x4*)(dst0 + (mt*16 + l4*4)*4) = acc[nt];
        }
    }
    __syncthreads();

    // ---- epilogue: z = exp(alpha*tanh(log_s)+beta)*x + t ----
    {
        const float* rs3f = (const float*)(lds + RS3_OFF);
        #pragma unroll
        for (int m = 0; m < 8; ++m) {
            const int e = tid + m*512;
            const int c = e >> 6, tl = e & 63;
            const float ls = rs3f[tl*132 + c];
            const float tv = rs3f[tl*132 + c + 64];
            // tanh(ls) = 1 - 2/(exp(2*ls)+1)  (saturates correctly at +-inf)
            const float e2 = __expf(2.f * ls);
            const float th = fmaf(-2.f, __builtin_amdgcn_rcpf(e2 + 1.f), 1.f);
            const float lsv = fmaf(alpha[c], th, beta[c]);
            out[((size_t)b*C_ + c)*T_ + t0 + tl] = fmaf(__expf(lsv), xv[m], tv);
        }
    }
}

extern "C" void kernel_launch(void* const* d_in, const int* in_sizes, int n_in,
                              void* d_out, int out_size, void* d_ws, size_t ws_size,
                              hipStream_t stream) {
    const float* x     = (const float*)d_in[0];
    const float* w_in  = (const float*)d_in[1];
    const float* b_in  = (const float*)d_in[2];
    const float* w_mid = (const float*)d_in[3];
    const float* b_mid = (const float*)d_in[4];
    const float* w_out = (const float*)d_in[5];
    const float* b_out = (const float*)d_in[6];
    const float* alpha = (const float*)d_in[7];
    const float* beta  = (const float*)d_in[8];
    float* out = (float*)d_out;

    if (ws_size < (size_t)AW_TOTAL) return;

    hipLaunchKernelGGL(pack_w, dim3(168), dim3(256), 0, stream,
                       w_in, w_mid, w_out, (unsigned short*)d_ws);
    hipLaunchKernelGGL(arflow_mfma, dim3(T_/TT, B_), dim3(512), 0, stream,
                       x, b_in, b_mid, b_out, alpha, beta, (const char*)d_ws, out);
}